// Round 15
// baseline (153.162 us; speedup 1.0000x reference)
//
#include <hip/hip_runtime.h>
#include <hip/hip_bf16.h>

// NonLocalBlock B=4,C=256,H=W=64 (N=4096) — round 19.
//  attn: byte-identical to r18 (session best, 152.4us total / 70.5us attn).
//  qkv I/O repair (the ~82us non-attn residue diagnostic):
//   (1) transpose loads float4-vectorized: 16 VMEM instr/thread (was 64
//       scalar f32) — Common-mistake #2 fix, same lines touched.
//   (2) K/V stores LDS-bounced: acc -> fp8 into dead xT (K linear [n][o];
//       V pre-arranged in chunked-local offsets), then linear 16KB copy at
//       16B/lane full-line stores (was 64 byte-scatter instr/thread).
//  Numerics identical (same f2fp8 values, rerouted). wcvt unchanged.
// ws = K8 | V8 | W8(bf16) | W8f(fp8 K,V) = 8.6 MiB.

typedef __attribute__((ext_vector_type(4))) short s16x4;
typedef __attribute__((ext_vector_type(8))) short s16x8;
typedef __attribute__((ext_vector_type(16))) float f32x16;
typedef __attribute__((ext_vector_type(4))) int i32x4;
typedef __attribute__((ext_vector_type(8))) int i32x8;

#define MFMA32(a, b, c)   __builtin_amdgcn_mfma_f32_32x32x16_bf16((a), (b), (c), 0, 0, 0)
// scaled fp8 K=64. MFMASC: scales 1.0/1.0.  MFMASC_Q: one scale 2^-4 (123)
// -> product scaled by 2^-4; with Q pre-scaled by log2e this equals SC.
#define MFMASC(a, b, c)   __builtin_amdgcn_mfma_scale_f32_32x32x64_f8f6f4((a), (b), (c), 0, 0, 0, 127, 0, 127)
#define MFMASC_Q(a, b, c) __builtin_amdgcn_mfma_scale_f32_32x32x64_f8f6f4((a), (b), (c), 0, 0, 0, 123, 0, 127)

constexpr int Cc = 256;
constexpr int Nn = 4096;

__device__ inline short f2bf(float f) {
    unsigned int u = __builtin_bit_cast(unsigned int, f);
    u = (u + 0x7fffu + ((u >> 16) & 1u)) >> 16;   // RNE
    return (short)u;
}
__device__ inline unsigned char f2fp8(float f) {   // f32 -> OCP e4m3, RNE-sat
    return (unsigned char)(__builtin_amdgcn_cvt_pk_fp8_f32(f, f, 0, false) & 0xff);
}
__device__ inline i32x8 cat8(i32x4 lo, i32x4 hi) {
    i32x8 r;
    r[0] = lo[0]; r[1] = lo[1]; r[2] = lo[2]; r[3] = lo[3];
    r[4] = hi[0]; r[5] = hi[1]; r[6] = hi[2]; r[7] = hi[3];
    return r;
}

__device__ inline void gl_lds16(const void* g, void* l) {
    // async global->LDS, 16 B/lane; LDS dest = wave-uniform base + lane*16
    __builtin_amdgcn_global_load_lds((const unsigned int*)g, (unsigned int*)l, 16, 0, 0);
}

// 32x32 MFMA C/D (shape-determined, dtype-independent):
//   col=lane&31, row=(r&3)+8*(r>>2)+4*(lane>>5)
// A/B frags feed identical per-lane byte->c maps -> dot product exact.

// W8 bf16 chunked fragment: row in [0,256), kc = 8-elem chunk index
#define WFRAG(Wm, row, kc) (*(const s16x8*)&(Wm)[(size_t)(kc)*2048 + (size_t)(row)*8])
// W8f fp8 chunked: [c>>4][o][c&15]; 16B granule g of row o at (g*256+o)*16
#define WF8(Wf, row, g) (*(const i32x4*)&(Wf)[((size_t)(g)*256 + (row)) * 16])

// ---------------------------------------------------------------- wcvt
// fp32 [o][c] -> bf16 chunked W8 (all 4 mats) + fp8 chunked W8f (Wk, Wv)
__global__ __launch_bounds__(256, 4) void wcvt_kernel(
    const float* __restrict__ wq, const float* __restrict__ wk,
    const float* __restrict__ wv, const float* __restrict__ wp,
    short* __restrict__ W, unsigned char* __restrict__ W8f)
{
    const int m = blockIdx.y;
    const float* src = (m == 0) ? wq : (m == 1) ? wk : (m == 2) ? wv : wp;
    const int idx = (blockIdx.x * 256 + threadIdx.x) * 8;
    const int o = idx >> 8, c0 = idx & 255;
    float4 a = *(const float4*)(src + idx);
    float4 b = *(const float4*)(src + idx + 4);
    s16x8 p = { f2bf(a.x), f2bf(a.y), f2bf(a.z), f2bf(a.w),
                f2bf(b.x), f2bf(b.y), f2bf(b.z), f2bf(b.w) };
    *(s16x8*)(W + m * 65536 + ((size_t)(c0 >> 3) * 256 + o) * 8) = p;
    if (m == 1 || m == 2) {                       // fp8 copy for qkv GEMMs
        unsigned char* Wf = W8f + (m - 1) * 65536;
        int w0 = __builtin_amdgcn_cvt_pk_fp8_f32(a.x, a.y, 0, false);
        w0 = __builtin_amdgcn_cvt_pk_fp8_f32(a.z, a.w, w0, true);
        int w1 = __builtin_amdgcn_cvt_pk_fp8_f32(b.x, b.y, 0, false);
        w1 = __builtin_amdgcn_cvt_pk_fp8_f32(b.z, b.w, w1, true);
        unsigned char* dst = Wf + (((size_t)(c0 >> 4) * 256 + o) * 16) + (c0 & 15);
        *(int*)(dst) = w0; *(int*)(dst + 4) = w1;
    }
}

// ---------------------------------------------------------------- qkv (K,V only; MX-fp8 GEMMs, repaired I/O)
// grid (64 n-tiles, 4 b, 2 mat), 256 thr.
__global__ __launch_bounds__(256, 4) void qkv_kernel(
    const float* __restrict__ x, const unsigned char* __restrict__ W8f,
    const float* __restrict__ bk, const float* __restrict__ bv,
    unsigned char* __restrict__ KT, unsigned char* __restrict__ V)
{
    const int nt = blockIdx.x, b = blockIdx.y, mat = blockIdx.z;  // 0=K 1=V
    const int n0 = nt * 64;
    const unsigned char* Wf = W8f + mat * 65536;
    const float* bias = (mat == 0) ? bk : bv;
    const int t = threadIdx.x, lane = t & 63, wid = t >> 6, h = lane >> 5, l31 = lane & 31;

    __shared__ alignas(16) unsigned char xT[16384];   // fp8 swizzled; later KO/VO

    const float* xb = x + (size_t)b * Cc * Nn;
    #pragma unroll
    for (int r = 0; r < 4; ++r) {                  // float4 transpose+quant
        int c4 = r*16 + (t >> 4);                  // c = 4*c4
        int nb = (t & 15) * 4;                     // 4 consecutive n
        float4 L0 = *(const float4*)(xb + (size_t)(4*c4 + 0) * Nn + n0 + nb);
        float4 L1 = *(const float4*)(xb + (size_t)(4*c4 + 1) * Nn + n0 + nb);
        float4 L2 = *(const float4*)(xb + (size_t)(4*c4 + 2) * Nn + n0 + nb);
        float4 L3 = *(const float4*)(xb + (size_t)(4*c4 + 3) * Nn + n0 + nb);
        const float* p0 = (const float*)&L0;
        const float* p1 = (const float*)&L1;
        const float* p2 = (const float*)&L2;
        const float* p3 = (const float*)&L3;
        #pragma unroll
        for (int i = 0; i < 4; ++i) {              // pack c-direction per n
            int w = __builtin_amdgcn_cvt_pk_fp8_f32(p0[i], p1[i], 0, false);
            w = __builtin_amdgcn_cvt_pk_fp8_f32(p2[i], p3[i], w, true);
            int n = nb + i;
            *(int*)(xT + n*256 + ((((c4 >> 2) ^ (n & 15)) << 4) | ((c4 & 3) * 4))) = w;
        }
    }
    __syncthreads();

    f32x16 acc[4];
    #pragma unroll
    for (int s = 0; s < 4; ++s)
        #pragma unroll
        for (int r = 0; r < 16; ++r) acc[s][r] = 0.f;

    if (mat == 0) {
        // K: D[n][o] = sum_c xT[n][c] Wk[o][c]  (A = xT fp8, B = Wf fp8)
        const int mw = wid & 1, nwb = (wid >> 1) * 4;
        const int arow = mw*32 + l31, asw = arow & 15;
        #pragma unroll
        for (int q = 0; q < 4; ++q) {
            i32x4 alo = *(const i32x4*)(xT + arow*256 + (((q*4 + h*2 + 0) ^ asw) << 4));
            i32x4 ahi = *(const i32x4*)(xT + arow*256 + (((q*4 + h*2 + 1) ^ asw) << 4));
            i32x8 a = cat8(alo, ahi);
            #pragma unroll
            for (int s = 0; s < 4; ++s) {
                int o = (nwb + s)*32 + l31;
                i32x8 bb = cat8(WF8(Wf, o, q*4 + h*2 + 0), WF8(Wf, o, q*4 + h*2 + 1));
                acc[s] = MFMASC(a, bb, acc[s]);
            }
        }
        __syncthreads();                           // xT reads done before overwrite
        // bounce: acc -> fp8 KO[n][o] (linear 16KB over xT)
        #pragma unroll
        for (int s = 0; s < 4; ++s) {
            int o = (nwb + s)*32 + l31;
            float bia = bias[o];
            #pragma unroll
            for (int r = 0; r < 16; ++r) {
                int n = mw*32 + (r & 3) + 8*(r >> 2) + 4*h;
                xT[n*256 + o] = f2fp8(acc[s][r] + bia);
            }
        }
        __syncthreads();
        // coalesced 16KB copy: rows n0..n0+63 of fp8 [n][c] are contiguous
        unsigned char* dst = KT + (size_t)b * Nn * Cc + (size_t)n0 * 256;
        #pragma unroll
        for (int it2 = 0; it2 < 4; ++it2) {
            int idx = it2*256 + t;
            *(i32x4*)(dst + idx*16) = *(const i32x4*)(xT + idx*16);
        }
    } else {
        // V: D[o][n] = sum_c Wv[o][c] xT[n][c]  (A = Wf fp8, B = xT fp8)
        const int b0r = 0 + l31, b1r = 32 + l31;
        #pragma unroll
        for (int q = 0; q < 4; ++q) {
            int g0 = q*4 + h*2 + 0, g1 = q*4 + h*2 + 1;
            i32x8 a0 = cat8(WF8(Wf, (wid*2 + 0)*32 + l31, g0), WF8(Wf, (wid*2 + 0)*32 + l31, g1));
            i32x8 a1 = cat8(WF8(Wf, (wid*2 + 1)*32 + l31, g0), WF8(Wf, (wid*2 + 1)*32 + l31, g1));
            i32x8 b0 = cat8(*(const i32x4*)(xT + b0r*256 + ((g0 ^ (b0r & 15)) << 4)),
                            *(const i32x4*)(xT + b0r*256 + ((g1 ^ (b0r & 15)) << 4)));
            i32x8 b1 = cat8(*(const i32x4*)(xT + b1r*256 + ((g0 ^ (b1r & 15)) << 4)),
                            *(const i32x4*)(xT + b1r*256 + ((g1 ^ (b1r & 15)) << 4)));
            acc[0] = MFMASC(a0, b0, acc[0]);
            acc[1] = MFMASC(a0, b1, acc[1]);
            acc[2] = MFMASC(a1, b0, acc[2]);
            acc[3] = MFMASC(a1, b1, acc[3]);
        }
        __syncthreads();                           // xT reads done before overwrite
        // bounce: acc -> fp8 VO in chunked-local offsets (16KB over xT)
        #pragma unroll
        for (int sub = 0; sub < 4; ++sub) {
            int mc = sub >> 1, nc = sub & 1;
            int jl = nc*32 + l31;                  // j - n0
            #pragma unroll
            for (int r = 0; r < 16; ++r) {
                int o = (wid*2 + mc)*32 + (r & 3) + 8*(r >> 2) + 4*h;
                xT[(jl >> 3)*2048 + o*8 + (jl & 7)] = f2fp8(acc[sub][r] + bias[o]);
            }
        }
        __syncthreads();
        // coalesced 16KB copy: chunk groups (n0>>3)..(n0>>3)+7 contiguous
        unsigned char* dst = V + (size_t)b * Cc * Nn + (size_t)(n0 >> 3) * 2048;
        #pragma unroll
        for (int it2 = 0; it2 < 4; ++it2) {
            int idx = it2*256 + t;
            *(i32x4*)(dst + idx*16) = *(const i32x4*)(xT + idx*16);
        }
    }
}

// ---------------------------------------------------------------- attn (+Q, +proj fused; MX fp8 core)
// BYTE-IDENTICAL to r18.
__global__ __launch_bounds__(512, 2) void attn_kernel(
    const unsigned char* __restrict__ KTg, const unsigned char* __restrict__ Vg,
    const short* __restrict__ Wg, const float* __restrict__ bq,
    const float* __restrict__ bp, const float* __restrict__ xg,
    float* __restrict__ outg)
{
    const int bid = blockIdx.x;
    const int b  = (bid & 7) >> 1;              // batch per XCD pair
    const int qt = ((bid >> 3) << 1) | (bid & 1);
    const int i0 = qt * 64;

    const int t = threadIdx.x, lane = t & 63, wid = t >> 6, h = lane >> 5, l31 = lane & 31;

    __shared__ alignas(16) char LDS[66304];
    char* KsB = LDS;                            // [2][64][256] fp8 K staging
    unsigned char* FqB = (unsigned char*)(LDS + 32768);  // [64][256] fp8 Q*log2e
    char* PsB = LDS + 49152;                    // [2][64][80] fp8 P
    float* lpart = (float*)(LDS + 65536);       // [2][64]
    float* linv  = (float*)(LDS + 66048);       // [64]

    const unsigned char* Kb = KTg + (size_t)b * Nn * Cc;  // fp8 [j][c]
    const unsigned char* Vb = Vg  + (size_t)b * Cc * Nn;  // fp8 chunked V8
    const float* xb = xg + (size_t)b * Cc * Nn;

    const float L2E = 1.4426950408889634f;      // log2(e); with 2^-4 MX scale
    f32x16 oacc[4];                             //   product scale = C^-0.5*log2e

    // ---------------- prologue: Q[i0..i0+63][256] in-kernel (bf16 GEMM -> fp8 Fq)
    {
        short* xTp = (short*)LDS;                // 64 rows x 512 B bf16 (over Ks)
        #pragma unroll
        for (int r = 0; r < 8; ++r) {            // transpose+cvt 64n x 256c
            int g = r * 512 + t;
            int n = g & 63, cg = g >> 6;         // c = 4*cg
            float f0 = xb[(size_t)(4*cg + 0) * Nn + i0 + n];
            float f1 = xb[(size_t)(4*cg + 1) * Nn + i0 + n];
            float f2 = xb[(size_t)(4*cg + 2) * Nn + i0 + n];
            float f3 = xb[(size_t)(4*cg + 3) * Nn + i0 + n];
            s16x4 p = { f2bf(f0), f2bf(f1), f2bf(f2), f2bf(f3) };
            int bcol = (((cg >> 1) ^ (n & 15)) << 4) + (cg & 1) * 8;
            *(s16x4*)((char*)xTp + n * 512 + bcol) = p;
        }
        __syncthreads();

        const short* Wq = Wg;                    // mat 0 chunked bf16
        f32x16 qa[2];
        #pragma unroll
        for (int s = 0; s < 2; ++s)
            #pragma unroll
            for (int r = 0; r < 16; ++r) qa[s][r] = 0.f;
        #pragma unroll 4
        for (int kk = 0; kk < 16; ++kk) {
            int gsw = ((kk*2 + h) ^ (l31 & 15)) << 4;
            s16x8 a0 = *(const s16x8*)((char*)xTp + ( 0 + l31) * 512 + gsw);
            s16x8 a1 = *(const s16x8*)((char*)xTp + (32 + l31) * 512 + gsw);
            s16x8 bb = WFRAG(Wq, wid*32 + l31, kk*2 + h);
            qa[0] = MFMA32(a0, bb, qa[0]);
            qa[1] = MFMA32(a1, bb, qa[1]);
        }
        // (Q + bq)*log2e -> Fq fp8 (16B-granule XOR swizzle on o)
        const int o = wid*32 + l31;
        const float bo = bq[o];
        #pragma unroll
        for (int mw2 = 0; mw2 < 2; ++mw2)
            #pragma unroll
            for (int r = 0; r < 16; ++r) {
                int n = mw2*32 + (r & 3) + 8*(r >> 2) + 4*h;
                FqB[n*256 + (((o >> 4) ^ (n & 15)) << 4) + (o & 15)] =
                    f2fp8((qa[mw2][r] + bo) * L2E);
            }
    }
    __syncthreads();

    if (wid < 4) {
        // ---------------- producer: S = K Q^T * SC (MX-scaled), exp2, P fp8
        const int w4 = wid, mj = w4 >> 1, ni = w4 & 1;

        i32x8 qf[4];                             // 32B fp8 frags from Fq
        {
            const int qrow = ni*32 + l31, qsw = qrow & 15;
            #pragma unroll
            for (int q = 0; q < 4; ++q) {
                i32x4 lo = *(const i32x4*)(FqB + qrow*256 + (((q*4 + h*2 + 0) ^ qsw) << 4));
                i32x4 hi = *(const i32x4*)(FqB + qrow*256 + (((q*4 + h*2 + 1) ^ qsw) << 4));
                qf[q] = cat8(lo, hi);
            }
        }
        float lacc = 0.f;                        // h-private; combined post-loop
        const int rl = mj*32 + l31;              // A-frag row (j)
        const int ip = ni*32 + l31;
        const int rsw = rl & 15;

        for (int tt = 0; tt < 66; ++tt) {
            if (tt < 64) {                       // stage K tile tt: 4 gl_lds/wave
                const int kb = tt & 1;
                #pragma unroll
                for (int it = 0; it < 4; ++it) {
                    int r = w4*16 + it*4 + (lane >> 4);
                    int g = (lane & 15) ^ (r & 15);
                    const unsigned char* gp = Kb + (size_t)(tt*64 + r) * Cc + g*16;
                    char* lp = KsB + kb*16384 + (w4*16 + it*4)*256;  // wave-uniform
                    gl_lds16(gp, lp);
                }
            }
            if (tt >= 1 && tt < 65) {
                const int jt = tt - 1, kb = jt & 1;
                const char* abase = KsB + kb*16384 + rl*256;
                f32x16 s;
                #pragma unroll
                for (int r = 0; r < 16; ++r) s[r] = 0.f;
                #pragma unroll
                for (int q = 0; q < 4; ++q) {
                    i32x4 lo = *(const i32x4*)(abase + (((q*4 + h*2 + 0) ^ rsw) << 4));
                    i32x4 hi = *(const i32x4*)(abase + (((q*4 + h*2 + 1) ^ rsw) << 4));
                    s = MFMASC_Q(cat8(lo, hi), qf[q], s);
                }
                float ps[16], lsum = 0.f;
                #pragma unroll
                for (int r = 0; r < 16; ++r) {
                    float e = exp2f(s[r]);       // scale already folded in
                    ps[r] = e; lsum += e;
                }
                lacc += lsum;                    // no per-window shfl
                char* pw = PsB + kb*5120 + ip*80 + mj*32 + 4*h;
                #pragma unroll
                for (int g = 0; g < 4; ++g) {    // pack 4 fp8 via 2 cvt_pk
                    int w = __builtin_amdgcn_cvt_pk_fp8_f32(ps[4*g+0], ps[4*g+1], 0, false);
                    w = __builtin_amdgcn_cvt_pk_fp8_f32(ps[4*g+2], ps[4*g+3], w, true);
                    *(int*)(pw + g*8) = w;
                }
            }
            __syncthreads();                     // producer: full drain (Ks + Ps publish)
        }
        lacc += __shfl_xor(lacc, 32);            // combine h-halves once
        if (h == 0) lpart[mj*64 + ip] = lacc;
    } else {
        // ---------------- consumer: O^T[c][i] += V[c][j] P[i][j] (K=64 scaled fp8)
        const int w2 = wid - 4;
        #pragma unroll
        for (int s = 0; s < 4; ++s)
            #pragma unroll
            for (int r = 0; r < 16; ++r) oacc[s][r] = 0.f;

        i32x8 vA0, vA1, vB0, vB1;
        const unsigned char* vb0 = Vb + (size_t)(w2*64 +  0 + l31) * 8;
        const unsigned char* vb1 = Vb + (size_t)(w2*64 + 32 + l31) * 8;

        for (int tp = 0; tp < 33; ++tp) {
            const int t0 = tp*2, t1 = t0 + 1;
            // even step t0: issue tile t0-1 -> vA ; consume tile t0-2 from vB
            if (t0 >= 1 && t0 <= 64) {
                const size_t jc = (size_t)(t0 - 1) * 8;
                #pragma unroll
                for (int m = 0; m < 4; ++m) {
                    long v0 = *(const long*)(vb0 + (jc + h*4 + m) * 2048);
                    long v1 = *(const long*)(vb1 + (jc + h*4 + m) * 2048);
                    vA0[2*m] = (int)v0; vA0[2*m+1] = (int)((unsigned long)v0 >> 32);
                    vA1[2*m] = (int)v1; vA1[2*m+1] = (int)((unsigned long)v1 >> 32);
                }
            }
            if (t0 >= 2) {
                const int pb = (t0 - 2) & 1;
                const char* pr = PsB + pb*5120 + l31*80 + h*32;
                i32x8 p0 = cat8(*(const i32x4*)(pr),        *(const i32x4*)(pr + 16));
                i32x8 p1 = cat8(*(const i32x4*)(pr + 2560), *(const i32x4*)(pr + 2576));
                oacc[0] = MFMASC(vB0, p0, oacc[0]);
                oacc[1] = MFMASC(vB0, p1, oacc[1]);
                oacc[2] = MFMASC(vB1, p0, oacc[2]);
                oacc[3] = MFMASC(vB1, p1, oacc[3]);
            }
            asm volatile("s_barrier" ::: "memory");   // no drain: V stays in flight
            // odd step t1: issue tile t1-1 -> vB ; consume tile t1-2 from vA
            if (t1 <= 64) {
                const size_t jc = (size_t)(t1 - 1) * 8;
                #pragma unroll
                for (int m = 0; m < 4; ++m) {
                    long v0 = *(const long*)(vb0 + (jc + h*4 + m) * 2048);
                    long v1 = *(const long*)(vb1 + (jc + h*4 + m) * 2048);
                    vB0[2*m] = (int)v0; vB0[2*m+1] = (int)((unsigned long)v0 >> 32);
                    vB1[2*m] = (int)v1; vB1[2*m+1] = (int)((unsigned long)v1 >> 32);
                }
            }
            if (t1 >= 2) {
                const int pb = (t1 - 2) & 1;
                const char* pr = PsB + pb*5120 + l31*80 + h*32;
                i32x8 p0 = cat8(*(const i32x4*)(pr),        *(const i32x4*)(pr + 16));
                i32x8 p1 = cat8(*(const i32x4*)(pr + 2560), *(const i32x4*)(pr + 2576));
                oacc[0] = MFMASC(vA0, p0, oacc[0]);
                oacc[1] = MFMASC(vA0, p1, oacc[1]);
                oacc[2] = MFMASC(vA1, p0, oacc[2]);
                oacc[3] = MFMASC(vA1, p1, oacc[3]);
            }
            asm volatile("s_barrier" ::: "memory");
        }
    }

    // ---------------- epilogue A: normalize, LDS-transpose O -> T[n][c] (bf16)
    __syncthreads();
    if (t < 64) linv[t] = 1.0f / (lpart[t] + lpart[64 + t]);
    __syncthreads();
    short (*T)[264] = (short(*)[264])LDS;       // overlays Ks+Fq head (dead)
    if (wid >= 4) {
        const int w2 = wid - 4;
        #pragma unroll
        for (int sub = 0; sub < 4; ++sub) {
            int mc = sub >> 1, nc = sub & 1;
            int ip = nc*32 + l31;
            float rl2 = linv[ip];
            #pragma unroll
            for (int r = 0; r < 16; ++r) {
                int c = w2*64 + mc*32 + (r & 3) + 8*(r >> 2) + 4*h;
                T[ip][c] = f2bf(oacc[sub][r] * rl2);
            }
        }
    }
    __syncthreads();

    // ---------------- epilogue B: fused proj (bf16). D[n][o] = sum_c T[n][c] Wp[o][c]
    {
        const short* Wp = Wg + 3 * 65536;
        f32x16 acc2[2];
        #pragma unroll
        for (int s = 0; s < 2; ++s)
            #pragma unroll
            for (int r = 0; r < 16; ++r) acc2[s][r] = 0.f;

        #pragma unroll 4
        for (int kk = 0; kk < 16; ++kk) {
            s16x8 a0 = *(const s16x8*)&T[ 0 + l31][kk*16 + h*8];
            s16x8 a1 = *(const s16x8*)&T[32 + l31][kk*16 + h*8];
            s16x8 bb = WFRAG(Wp, wid*32 + l31, kk*2 + h);
            acc2[0] = MFMA32(a0, bb, acc2[0]);
            acc2[1] = MFMA32(a1, bb, acc2[1]);
        }
        __syncthreads();                         // all waves done reading T

        // bounce acc2 through XOR-swizzled fp32 tile F[n][o^(n&31)]
        float (*F)[256] = (float(*)[256])LDS;    // 64n x 256o fp32 = 64 KB
        {
            const int o = wid*32 + l31;
            #pragma unroll
            for (int nh = 0; nh < 2; ++nh) {
                #pragma unroll
                for (int r = 0; r < 16; ++r) {
                    int n = nh*32 + (r & 3) + 8*(r >> 2) + 4*h;
                    F[n][o ^ (n & 31)] = acc2[nh][r];
                }
            }
        }
        __syncthreads();

        // coalesced residual+store: lanes take consecutive n, fixed o
        float* ob = outg + (size_t)b * Cc * Nn;
        #pragma unroll 8
        for (int it = 0; it < 32; ++it) {
            int o = it*8 + wid;
            size_t idx = (size_t)o * Nn + i0 + lane;
            ob[idx] = xb[idx] + F[lane][o ^ (lane & 31)] + bp[o];
        }
    }
}

// ---------------------------------------------------------------- launch
extern "C" void kernel_launch(void* const* d_in, const int* in_sizes, int n_in,
                              void* d_out, int out_size, void* d_ws, size_t ws_size,
                              hipStream_t stream)
{
    const float* x  = (const float*)d_in[0];
    const float* wq = (const float*)d_in[1];
    const float* bq = (const float*)d_in[2];
    const float* wk = (const float*)d_in[3];
    const float* bk = (const float*)d_in[4];
    const float* wv = (const float*)d_in[5];
    const float* bv = (const float*)d_in[6];
    const float* wp = (const float*)d_in[7];
    const float* bp = (const float*)d_in[8];

    const size_t kvbytes = (size_t)4 * Nn * Cc;            // 4 MiB per fp8 buffer
    const size_t wel     = (size_t)4 * 65536;              // W8 bf16 shorts
    const size_t wfb     = (size_t)2 * 65536;              // W8f fp8 bytes
    const size_t need    = 2 * kvbytes + wel * sizeof(short) + wfb;   // ~8.6 MiB
    if (ws_size < need) return;
    unsigned char* KT = (unsigned char*)d_ws;   // [b][n][c] fp8
    unsigned char* V  = KT + kvbytes;           // [b] chunked V8 fp8
    short* Wbf = (short*)(V + kvbytes);         // 4 x chunked W8 bf16
    unsigned char* W8f = (unsigned char*)(Wbf + wel);  // 2 x chunked fp8 (Wk,Wv)
    (void)in_sizes; (void)n_in; (void)out_size;

    wcvt_kernel<<<dim3(32, 4), 256, 0, stream>>>(wq, wk, wv, wp, Wbf, W8f);
    qkv_kernel<<<dim3(64, 4, 2), 256, 0, stream>>>(x, W8f, bk, bv, KT, V);
    attn_kernel<<<dim3(256), 512, 0, stream>>>(KT, V, Wbf, bq, bp, x, (float*)d_out);
}